// Round 1
// baseline (942.998 us; speedup 1.0000x reference)
//
#include <hip/hip_runtime.h>
#include <hip/hip_bf16.h>
#include <stdint.h>

#define IN_F   4096
#define OUT_F  11008
#define TOKENS 4096
#define NELEM_W ((size_t)OUT_F * (size_t)IN_F)   // 45,088,768
#define NELEM_X ((size_t)TOKENS * (size_t)IN_F)  // 16,777,216

#define BM 128
#define BN 128
#define BK 32

typedef __attribute__((ext_vector_type(8))) short short8;
typedef __attribute__((ext_vector_type(4))) float floatx4;

__device__ __forceinline__ void gload_lds16(const void* g, void* l) {
  __builtin_amdgcn_global_load_lds((const __attribute__((address_space(1))) void*)g,
                                   (__attribute__((address_space(3))) void*)l,
                                   16, 0, 0);
}

// round-to-nearest-even fp32 -> bf16 bit pattern
__device__ __forceinline__ ushort f2bf(float f) {
  union { float f; uint32_t u; } a; a.f = f;
  uint32_t u = a.u;
  return (ushort)((u + 0x7FFFu + ((u >> 16) & 1u)) >> 16);
}

// ternary quantization in fp64 (match float64 reference threshold semantics)
__device__ __forceinline__ ushort qtern(float v, double a) {
  double d = (double)v;
  return d > a ? (ushort)0x3F80 : (d < -a ? (ushort)0xBF80 : (ushort)0);
}

// ---------------- kernel 1: sum(|W|) in fp64 ----------------
__global__ __launch_bounds__(256) void absmean_reduce(const float* __restrict__ w,
                                                      double* __restrict__ out) {
  size_t tid = (size_t)blockIdx.x * 256 + threadIdx.x;
  size_t stride = (size_t)gridDim.x * 256;
  const float4* w4 = (const float4*)w;
  size_t n4 = NELEM_W / 4;
  double s = 0.0;
  for (size_t i = tid; i < n4; i += stride) {
    float4 v = w4[i];
    s += (double)fabsf(v.x) + (double)fabsf(v.y) + (double)fabsf(v.z) + (double)fabsf(v.w);
  }
#pragma unroll
  for (int off = 32; off > 0; off >>= 1) s += __shfl_down(s, off, 64);
  __shared__ double sm[4];
  int lane = threadIdx.x & 63, wv = threadIdx.x >> 6;
  if (lane == 0) sm[wv] = s;
  __syncthreads();
  if (threadIdx.x == 0) atomicAdd(out, sm[0] + sm[1] + sm[2] + sm[3]);
}

// ---------------- kernel 2: x fp32 -> bf16 ----------------
__global__ __launch_bounds__(256) void convert_x(const float* __restrict__ x,
                                                 ushort* __restrict__ xb) {
  size_t i = ((size_t)blockIdx.x * 256 + threadIdx.x) * 8;
  float4 a = *(const float4*)(x + i);
  float4 b = *(const float4*)(x + i + 4);
  union { ushort s[8]; uint4 v; } u;
  u.s[0] = f2bf(a.x); u.s[1] = f2bf(a.y); u.s[2] = f2bf(a.z); u.s[3] = f2bf(a.w);
  u.s[4] = f2bf(b.x); u.s[5] = f2bf(b.y); u.s[6] = f2bf(b.z); u.s[7] = f2bf(b.w);
  *(uint4*)(xb + i) = u.v;
}

// ---------------- kernel 3: W fp32 -> ternary bf16 (+-1/0) ----------------
__global__ __launch_bounds__(256) void quantize_w(const float* __restrict__ w,
                                                  const double* __restrict__ asum,
                                                  ushort* __restrict__ wq) {
  double alpha = *asum * (1.0 / (double)NELEM_W);
  size_t i = ((size_t)blockIdx.x * 256 + threadIdx.x) * 8;
  float4 a = *(const float4*)(w + i);
  float4 b = *(const float4*)(w + i + 4);
  union { ushort s[8]; uint4 v; } u;
  u.s[0] = qtern(a.x, alpha); u.s[1] = qtern(a.y, alpha);
  u.s[2] = qtern(a.z, alpha); u.s[3] = qtern(a.w, alpha);
  u.s[4] = qtern(b.x, alpha); u.s[5] = qtern(b.y, alpha);
  u.s[6] = qtern(b.z, alpha); u.s[7] = qtern(b.w, alpha);
  *(uint4*)(wq + i) = u.v;
}

// ---------------- kernel 4: bf16 GEMM, C[m][n] = sum_k A[m][k]*B[n][k] ----------------
// A: [TOKENS][IN_F] bf16, B: [OUT_F][IN_F] ternary bf16. m97 structure:
// 128x128 block tile, BK=32, 4 waves (2x2), 4x4 16x16x32 MFMA per wave,
// global_load_lds width=16 staging (LDS dst = wave-uniform base + lane*16).
__global__ __launch_bounds__(256) void gemm_bt_bf16(
    const ushort* __restrict__ A, const ushort* __restrict__ B,
    const float* __restrict__ scale, const float* __restrict__ bias,
    float* __restrict__ C) {
  __shared__ __align__(16) ushort As[BM * BK];  // 8 KB
  __shared__ __align__(16) ushort Bs[BN * BK];  // 8 KB

  const int tid  = threadIdx.x;
  const int lane = tid & 63;
  const int wid  = tid >> 6;
  const int wm   = wid & 1;
  const int wn   = wid >> 1;

  const int row0 = blockIdx.y * BM;
  const int col0 = blockIdx.x * BN;

  // staging granules: 16B granule g covers LDS row g>>2, k-chunk (g&3)*8
  const int g0 = wid * 128 + lane;  // instr j=0
  const int g1 = g0 + 64;           // instr j=1
  const ushort* pa0 = A + (size_t)(row0 + (g0 >> 2)) * IN_F + (g0 & 3) * 8;
  const ushort* pa1 = A + (size_t)(row0 + (g1 >> 2)) * IN_F + (g1 & 3) * 8;
  const ushort* pb0 = B + (size_t)(col0 + (g0 >> 2)) * IN_F + (g0 & 3) * 8;
  const ushort* pb1 = B + (size_t)(col0 + (g1 >> 2)) * IN_F + (g1 & 3) * 8;
  ushort* sa0 = As + (wid * 128) * 8;  // wave-uniform LDS bases
  ushort* sa1 = sa0 + 64 * 8;
  ushort* sb0 = Bs + (wid * 128) * 8;
  ushort* sb1 = sb0 + 64 * 8;

  floatx4 acc[4][4] = {};
  const int quad = lane >> 4;
  const int r16  = lane & 15;

  for (int k0 = 0; k0 < IN_F; k0 += BK) {
    __syncthreads();  // previous iter's LDS reads done
    gload_lds16(pa0, sa0);
    gload_lds16(pa1, sa1);
    gload_lds16(pb0, sb0);
    gload_lds16(pb1, sb1);
    pa0 += BK; pa1 += BK; pb0 += BK; pb1 += BK;
    __syncthreads();  // staging complete (vmcnt drained by barrier)

    short8 af[4], bfr[4];
#pragma unroll
    for (int t = 0; t < 4; t++) {
      // A-operand layout: m = lane&15, k = quad*8 + j  -> contiguous 16B in LDS row
      af[t]  = *(const short8*)(As + (wm * 64 + t * 16 + r16) * BK + quad * 8);
      bfr[t] = *(const short8*)(Bs + (wn * 64 + t * 16 + r16) * BK + quad * 8);
    }
#pragma unroll
    for (int i = 0; i < 4; i++)
#pragma unroll
      for (int j = 0; j < 4; j++)
        acc[i][j] = __builtin_amdgcn_mfma_f32_16x16x32_bf16(af[i], bfr[j], acc[i][j], 0, 0, 0);
  }

  // epilogue: C/D layout col = lane&15, row = quad*4 + reg
#pragma unroll
  for (int i = 0; i < 4; i++) {
    const int mbase = row0 + wm * 64 + i * 16 + quad * 4;
#pragma unroll
    for (int j = 0; j < 4; j++) {
      const int n = col0 + wn * 64 + j * 16 + r16;
      const float sc = scale[n];
      const float bi = bias[n];
      float* cp = C + (size_t)mbase * OUT_F + n;
#pragma unroll
      for (int r = 0; r < 4; r++)
        cp[(size_t)r * OUT_F] = acc[i][j][r] * sc + bi;
    }
  }
}

// ---------------- fallback: fused fp32->bf16 quantize + GEMM (8B workspace) ----------------
__global__ __launch_bounds__(256) void gemm_fused_fp32(
    const float* __restrict__ X, const float* __restrict__ W,
    const double* __restrict__ asum,
    const float* __restrict__ scale, const float* __restrict__ bias,
    float* __restrict__ C) {
  __shared__ __align__(16) ushort As[BM * BK];
  __shared__ __align__(16) ushort Bs[BN * BK];
  const double alpha = *asum * (1.0 / (double)NELEM_W);

  const int tid  = threadIdx.x;
  const int lane = tid & 63;
  const int wid  = tid >> 6;
  const int wm   = wid & 1;
  const int wn   = wid >> 1;
  const int row0 = blockIdx.y * BM;
  const int col0 = blockIdx.x * BN;

  floatx4 acc[4][4] = {};
  const int quad = lane >> 4;
  const int r16  = lane & 15;

  for (int k0 = 0; k0 < IN_F; k0 += BK) {
    __syncthreads();
#pragma unroll
    for (int s = 0; s < 4; s++) {
      int g = tid + s * 256;          // float4 granule: 8 per 32-elem row
      int r = g >> 3, c = g & 7;
      float4 va = *(const float4*)(X + (size_t)(row0 + r) * IN_F + k0 + c * 4);
      ushort4 ua;
      ua.x = f2bf(va.x); ua.y = f2bf(va.y); ua.z = f2bf(va.z); ua.w = f2bf(va.w);
      *(ushort4*)(As + r * BK + c * 4) = ua;
      float4 vb = *(const float4*)(W + (size_t)(col0 + r) * IN_F + k0 + c * 4);
      ushort4 ub;
      ub.x = qtern(vb.x, alpha); ub.y = qtern(vb.y, alpha);
      ub.z = qtern(vb.z, alpha); ub.w = qtern(vb.w, alpha);
      *(ushort4*)(Bs + r * BK + c * 4) = ub;
    }
    __syncthreads();

    short8 af[4], bfr[4];
#pragma unroll
    for (int t = 0; t < 4; t++) {
      af[t]  = *(const short8*)(As + (wm * 64 + t * 16 + r16) * BK + quad * 8);
      bfr[t] = *(const short8*)(Bs + (wn * 64 + t * 16 + r16) * BK + quad * 8);
    }
#pragma unroll
    for (int i = 0; i < 4; i++)
#pragma unroll
      for (int j = 0; j < 4; j++)
        acc[i][j] = __builtin_amdgcn_mfma_f32_16x16x32_bf16(af[i], bfr[j], acc[i][j], 0, 0, 0);
  }

#pragma unroll
  for (int i = 0; i < 4; i++) {
    const int mbase = row0 + wm * 64 + i * 16 + quad * 4;
#pragma unroll
    for (int j = 0; j < 4; j++) {
      const int n = col0 + wn * 64 + j * 16 + r16;
      const float sc = scale[n];
      const float bi = bias[n];
      float* cp = C + (size_t)mbase * OUT_F + n;
#pragma unroll
      for (int r = 0; r < 4; r++)
        cp[(size_t)r * OUT_F] = acc[i][j][r] * sc + bi;
    }
  }
}

extern "C" void kernel_launch(void* const* d_in, const int* in_sizes, int n_in,
                              void* d_out, int out_size, void* d_ws, size_t ws_size,
                              hipStream_t stream) {
  const float* x     = (const float*)d_in[0];
  const float* w     = (const float*)d_in[1];
  const float* scale = (const float*)d_in[2];
  const float* bias  = (const float*)d_in[3];
  float* out = (float*)d_out;

  double* asum = (double*)d_ws;
  hipMemsetAsync(d_ws, 0, 8, stream);  // ws is re-poisoned 0xAA before every call
  absmean_reduce<<<1024, 256, 0, stream>>>(w, asum);

  const size_t offX = 64;
  const size_t offW = offX + NELEM_X * 2;
  const size_t need = offW + NELEM_W * 2;
  dim3 grid(OUT_F / BN, TOKENS / BM);

  if (ws_size >= need) {
    ushort* xb = (ushort*)((char*)d_ws + offX);
    ushort* wb = (ushort*)((char*)d_ws + offW);
    convert_x<<<(int)(NELEM_X / 2048), 256, 0, stream>>>(x, xb);
    quantize_w<<<(int)(NELEM_W / 2048), 256, 0, stream>>>(w, asum, wb);
    gemm_bt_bf16<<<grid, 256, 0, stream>>>(xb, wb, scale, bias, out);
  } else {
    gemm_fused_fp32<<<grid, 256, 0, stream>>>(x, w, asum, scale, bias, out);
  }
}

// Round 2
// 824.445 us; speedup vs baseline: 1.1438x; 1.1438x over previous
//
#include <hip/hip_runtime.h>
#include <hip/hip_bf16.h>
#include <stdint.h>

#define IN_F   4096
#define OUT_F  11008
#define TOKENS 4096
#define NELEM_W ((size_t)OUT_F * (size_t)IN_F)   // 45,088,768
#define NELEM_X ((size_t)TOKENS * (size_t)IN_F)  // 16,777,216

#define BM 128
#define BN 128
#define BK 32

typedef __attribute__((ext_vector_type(8))) short short8;
typedef __attribute__((ext_vector_type(4))) float floatx4;

__device__ __forceinline__ void gload_lds16(const void* g, void* l) {
  __builtin_amdgcn_global_load_lds((const __attribute__((address_space(1))) void*)g,
                                   (__attribute__((address_space(3))) void*)l,
                                   16, 0, 0);
}

// round-to-nearest-even fp32 -> bf16 bit pattern
__device__ __forceinline__ ushort f2bf(float f) {
  union { float f; uint32_t u; } a; a.f = f;
  uint32_t u = a.u;
  return (ushort)((u + 0x7FFFu + ((u >> 16) & 1u)) >> 16);
}

// ternary quantization in fp64 (match float64 reference threshold semantics)
__device__ __forceinline__ ushort qtern(float v, double a) {
  double d = (double)v;
  return d > a ? (ushort)0x3F80 : (d < -a ? (ushort)0xBF80 : (ushort)0);
}

// ---------------- kernel 1: sum(|W|) in fp64 ----------------
// 4 independent accumulators to break the dependent f64-add chain.
__global__ __launch_bounds__(256) void absmean_reduce(const float* __restrict__ w,
                                                      double* __restrict__ out) {
  size_t tid = (size_t)blockIdx.x * 256 + threadIdx.x;
  size_t stride = (size_t)gridDim.x * 256;
  const float4* w4 = (const float4*)w;
  size_t n4 = NELEM_W / 4;
  double s0 = 0.0, s1 = 0.0, s2 = 0.0, s3 = 0.0;
  for (size_t i = tid; i < n4; i += stride) {
    float4 v = w4[i];
    s0 += (double)fabsf(v.x); s1 += (double)fabsf(v.y);
    s2 += (double)fabsf(v.z); s3 += (double)fabsf(v.w);
  }
  double s = (s0 + s1) + (s2 + s3);
#pragma unroll
  for (int off = 32; off > 0; off >>= 1) s += __shfl_down(s, off, 64);
  __shared__ double sm[4];
  int lane = threadIdx.x & 63, wv = threadIdx.x >> 6;
  if (lane == 0) sm[wv] = s;
  __syncthreads();
  if (threadIdx.x == 0) atomicAdd(out, (sm[0] + sm[1]) + (sm[2] + sm[3]));
}

// ---------------- kernel 2: x fp32 -> bf16 ----------------
__global__ __launch_bounds__(256) void convert_x(const float* __restrict__ x,
                                                 ushort* __restrict__ xb) {
  size_t i = ((size_t)blockIdx.x * 256 + threadIdx.x) * 8;
  float4 a = *(const float4*)(x + i);
  float4 b = *(const float4*)(x + i + 4);
  union { ushort s[8]; uint4 v; } u;
  u.s[0] = f2bf(a.x); u.s[1] = f2bf(a.y); u.s[2] = f2bf(a.z); u.s[3] = f2bf(a.w);
  u.s[4] = f2bf(b.x); u.s[5] = f2bf(b.y); u.s[6] = f2bf(b.z); u.s[7] = f2bf(b.w);
  *(uint4*)(xb + i) = u.v;
}

// ---------------- kernel 3: W fp32 -> ternary bf16 (+-1/0) ----------------
__global__ __launch_bounds__(256) void quantize_w(const float* __restrict__ w,
                                                  const double* __restrict__ asum,
                                                  ushort* __restrict__ wq) {
  double alpha = *asum * (1.0 / (double)NELEM_W);
  size_t i = ((size_t)blockIdx.x * 256 + threadIdx.x) * 8;
  float4 a = *(const float4*)(w + i);
  float4 b = *(const float4*)(w + i + 4);
  union { ushort s[8]; uint4 v; } u;
  u.s[0] = qtern(a.x, alpha); u.s[1] = qtern(a.y, alpha);
  u.s[2] = qtern(a.z, alpha); u.s[3] = qtern(a.w, alpha);
  u.s[4] = qtern(b.x, alpha); u.s[5] = qtern(b.y, alpha);
  u.s[6] = qtern(b.z, alpha); u.s[7] = qtern(b.w, alpha);
  *(uint4*)(wq + i) = u.v;
}

// ---------------- kernel 4: bf16 GEMM, C[m][n] = sum_k A[m][k]*B[n][k] ----------------
// 128x128 tile, BK=32, 4 waves (2x2), 4x4 16x16x32 MFMA per wave.
// - XOR-swizzled LDS slot map: 16B granule (row, col') stores global k-chunk
//   col = col' ^ ((row>>1)&3). Implemented by permuting the GLOBAL source per
//   lane (LDS dst of global_load_lds is forced lane-contiguous). Fragment
//   reads then hit 8 bank-groups 2-way each -> conflict-free per m136.
// - Single-barrier double-buffered pipeline: next tile's DMA issued after the
//   barrier, drained at the NEXT barrier -> one MFMA-stage of latency hiding.
// - Grid transposed: blockIdx.x = M-row (fastest) so concurrent blocks share
//   one B column-tile; B streams HBM once, A stays cache-hot.
__global__ __launch_bounds__(256) void gemm_bt_bf16(
    const ushort* __restrict__ A, const ushort* __restrict__ B,
    const float* __restrict__ scale, const float* __restrict__ bias,
    float* __restrict__ C) {
  __shared__ __align__(16) ushort As[2][BM * BK];  // 2 x 8 KB
  __shared__ __align__(16) ushort Bs[2][BN * BK];  // 2 x 8 KB

  const int tid  = threadIdx.x;
  const int lane = tid & 63;
  const int wid  = tid >> 6;
  const int wm   = wid & 1;
  const int wn   = wid >> 1;

  const int row0 = blockIdx.x * BM;  // x = rows (fastest) for B-tile L2 sharing
  const int col0 = blockIdx.y * BN;

  // staging: slot g (16B granule) holds row = g>>2, swizzled col.
  const int g0 = wid * 128 + lane;
  const int g1 = g0 + 64;
  const int r0s = g0 >> 2, c0s = (g0 & 3) ^ ((r0s >> 1) & 3);
  const int r1s = g1 >> 2, c1s = (g1 & 3) ^ ((r1s >> 1) & 3);
  const ushort* pa0 = A + (size_t)(row0 + r0s) * IN_F + c0s * 8;
  const ushort* pa1 = A + (size_t)(row0 + r1s) * IN_F + c1s * 8;
  const ushort* pb0 = B + (size_t)(col0 + r0s) * IN_F + c0s * 8;
  const ushort* pb1 = B + (size_t)(col0 + r1s) * IN_F + c1s * 8;
  const int ldsw = wid * 1024;  // wave-uniform LDS element offset (128 granules * 8)

  floatx4 acc[4][4] = {};
  const int quad = lane >> 4;
  const int r16  = lane & 15;
  // swizzled fragment column: col' = quad ^ ((r16>>1)&3), constant per lane
  const int cw = (quad ^ ((r16 >> 1) & 3)) * 8;

#define STAGE(b, koff)                                   \
  do {                                                   \
    gload_lds16(pa0 + (koff), &As[b][0] + ldsw);         \
    gload_lds16(pa1 + (koff), &As[b][0] + ldsw + 512);   \
    gload_lds16(pb0 + (koff), &Bs[b][0] + ldsw);         \
    gload_lds16(pb1 + (koff), &Bs[b][0] + ldsw + 512);   \
  } while (0)

  STAGE(0, 0);
  int buf = 0;
  for (int k0 = 0; k0 < IN_F; k0 += BK) {
    __syncthreads();  // drains own DMA (vmcnt) -> tile[buf] staged; prev reads done
    if (k0 + BK < IN_F) STAGE(buf ^ 1, k0 + BK);  // overlap with MFMA below

    short8 af[4], bfr[4];
#pragma unroll
    for (int t = 0; t < 4; t++) {
      af[t]  = *(const short8*)(&As[buf][0] + (wm * 64 + t * 16 + r16) * BK + cw);
      bfr[t] = *(const short8*)(&Bs[buf][0] + (wn * 64 + t * 16 + r16) * BK + cw);
    }
#pragma unroll
    for (int i = 0; i < 4; i++)
#pragma unroll
      for (int j = 0; j < 4; j++)
        acc[i][j] = __builtin_amdgcn_mfma_f32_16x16x32_bf16(af[i], bfr[j], acc[i][j], 0, 0, 0);
    buf ^= 1;
  }
#undef STAGE

  // epilogue: C/D layout col = lane&15, row = quad*4 + reg
#pragma unroll
  for (int i = 0; i < 4; i++) {
    const int mbase = row0 + wm * 64 + i * 16 + quad * 4;
#pragma unroll
    for (int j = 0; j < 4; j++) {
      const int n = col0 + wn * 64 + j * 16 + r16;
      const float sc = scale[n];
      const float bi = bias[n];
      float* cp = C + (size_t)mbase * OUT_F + n;
#pragma unroll
      for (int r = 0; r < 4; r++)
        cp[(size_t)r * OUT_F] = acc[i][j][r] * sc + bi;
    }
  }
}

// ---------------- fallback: fused fp32->bf16 quantize + GEMM (8B workspace) ----------------
__global__ __launch_bounds__(256) void gemm_fused_fp32(
    const float* __restrict__ X, const float* __restrict__ W,
    const double* __restrict__ asum,
    const float* __restrict__ scale, const float* __restrict__ bias,
    float* __restrict__ C) {
  __shared__ __align__(16) ushort As[BM * BK];
  __shared__ __align__(16) ushort Bs[BN * BK];
  const double alpha = *asum * (1.0 / (double)NELEM_W);

  const int tid  = threadIdx.x;
  const int lane = tid & 63;
  const int wid  = tid >> 6;
  const int wm   = wid & 1;
  const int wn   = wid >> 1;
  const int row0 = blockIdx.x * BM;
  const int col0 = blockIdx.y * BN;

  floatx4 acc[4][4] = {};
  const int quad = lane >> 4;
  const int r16  = lane & 15;

  for (int k0 = 0; k0 < IN_F; k0 += BK) {
    __syncthreads();
#pragma unroll
    for (int s = 0; s < 4; s++) {
      int g = tid + s * 256;
      int r = g >> 3, c = g & 7;
      float4 va = *(const float4*)(X + (size_t)(row0 + r) * IN_F + k0 + c * 4);
      ushort4 ua;
      ua.x = f2bf(va.x); ua.y = f2bf(va.y); ua.z = f2bf(va.z); ua.w = f2bf(va.w);
      *(ushort4*)(As + r * BK + c * 4) = ua;
      float4 vb = *(const float4*)(W + (size_t)(col0 + r) * IN_F + k0 + c * 4);
      ushort4 ub;
      ub.x = qtern(vb.x, alpha); ub.y = qtern(vb.y, alpha);
      ub.z = qtern(vb.z, alpha); ub.w = qtern(vb.w, alpha);
      *(ushort4*)(Bs + r * BK + c * 4) = ub;
    }
    __syncthreads();

    short8 af[4], bfr[4];
#pragma unroll
    for (int t = 0; t < 4; t++) {
      af[t]  = *(const short8*)(As + (wm * 64 + t * 16 + r16) * BK + quad * 8);
      bfr[t] = *(const short8*)(Bs + (wn * 64 + t * 16 + r16) * BK + quad * 8);
    }
#pragma unroll
    for (int i = 0; i < 4; i++)
#pragma unroll
      for (int j = 0; j < 4; j++)
        acc[i][j] = __builtin_amdgcn_mfma_f32_16x16x32_bf16(af[i], bfr[j], acc[i][j], 0, 0, 0);
  }

#pragma unroll
  for (int i = 0; i < 4; i++) {
    const int mbase = row0 + wm * 64 + i * 16 + quad * 4;
#pragma unroll
    for (int j = 0; j < 4; j++) {
      const int n = col0 + wn * 64 + j * 16 + r16;
      const float sc = scale[n];
      const float bi = bias[n];
      float* cp = C + (size_t)mbase * OUT_F + n;
#pragma unroll
      for (int r = 0; r < 4; r++)
        cp[(size_t)r * OUT_F] = acc[i][j][r] * sc + bi;
    }
  }
}

extern "C" void kernel_launch(void* const* d_in, const int* in_sizes, int n_in,
                              void* d_out, int out_size, void* d_ws, size_t ws_size,
                              hipStream_t stream) {
  const float* x     = (const float*)d_in[0];
  const float* w     = (const float*)d_in[1];
  const float* scale = (const float*)d_in[2];
  const float* bias  = (const float*)d_in[3];
  float* out = (float*)d_out;

  double* asum = (double*)d_ws;
  hipMemsetAsync(d_ws, 0, 8, stream);  // ws is re-poisoned 0xAA before every call
  absmean_reduce<<<2048, 256, 0, stream>>>(w, asum);

  const size_t offX = 64;
  const size_t offW = offX + NELEM_X * 2;
  const size_t need = offW + NELEM_W * 2;
  dim3 grid(TOKENS / BM, OUT_F / BN);  // x = rows (fastest)

  if (ws_size >= need) {
    ushort* xb = (ushort*)((char*)d_ws + offX);
    ushort* wb = (ushort*)((char*)d_ws + offW);
    convert_x<<<(int)(NELEM_X / 2048), 256, 0, stream>>>(x, xb);
    quantize_w<<<(int)(NELEM_W / 2048), 256, 0, stream>>>(w, asum, wb);
    gemm_bt_bf16<<<grid, 256, 0, stream>>>(xb, wb, scale, bias, out);
  } else {
    gemm_fused_fp32<<<grid, 256, 0, stream>>>(x, w, asum, scale, bias, out);
  }
}